// Round 5
// baseline (359.963 us; speedup 1.0000x reference)
//
#include <hip/hip_runtime.h>
#include <cstdint>
#include <cmath>

// Problem constants: N=100000, IN=64, HID=32, R=3, B=2, E=1600000, G=256, 4 layers
// CSR build: bucketed scatter (write locality), then per-bucket counting sort
// keyed by (node_lo, etype) -> edge lists are etype-SEGMENTED per node.
// Segment boundaries let the gather loops hoist the per-edge coefficient math.
#define DLO_BITS 7
#define DLO_MASK 127
#define SCAT_Q 2048

// ---------------- weight prep: W[m] = sum_b comp[m,b]*basis1[b]; W[3]=loop1 ---
__global__ __launch_bounds__(256) void prep_w(
    const float* __restrict__ basis1,   // [2,64,32]
    const float* __restrict__ w_comp,   // [4,3,2] (layer-0 slice)
    const float* __restrict__ loop1,    // [64,32]
    float* __restrict__ W)              // [4,64,32]
{
    int tid = blockIdx.x * 256 + threadIdx.x;
    if (tid < 8192) {
        int m = tid >> 11, io = tid & 2047;
        W[tid] = (m < 3)
            ? w_comp[m * 2] * basis1[io] + w_comp[m * 2 + 1] * basis1[2048 + io]
            : loop1[io];
    }
}

// ---------------- bucket count ----------------
__global__ __launch_bounds__(256) void count_kernel(
    const int* __restrict__ dst, int* __restrict__ bcnt, int E, int NB)
{
    __shared__ int cnt[1024];
    for (int i = threadIdx.x; i < NB; i += 256) cnt[i] = 0;
    __syncthreads();
    int base = blockIdx.x * SCAT_Q;
    #pragma unroll
    for (int i = 0; i < SCAT_Q / 256; ++i) {
        int e = base + i * 256 + threadIdx.x;
        if (e < E) atomicAdd(&cnt[dst[e] >> DLO_BITS], 1);
    }
    __syncthreads();
    for (int i = threadIdx.x; i < NB; i += 256)
        if (cnt[i]) atomicAdd(&bcnt[i], cnt[i]);
}

// ---------------- exclusive scan over NB (<=1024) buckets ---------------------
__global__ __launch_bounds__(1024) void scan_kernel(
    const int* __restrict__ bcnt, int* __restrict__ bbase,
    int* __restrict__ bcur, int NB)
{
    __shared__ int s[1024];
    int t = threadIdx.x;
    int v = (t < NB) ? bcnt[t] : 0;
    s[t] = v; __syncthreads();
    for (int off = 1; off < 1024; off <<= 1) {
        int u = (t >= off) ? s[t - off] : 0;
        __syncthreads();
        s[t] += u;
        __syncthreads();
    }
    if (t < NB) { int b = s[t] - v; bbase[t] = b; bcur[t] = b; }
}

// ---------------- bucketed scatter (runs per (block,bucket)) ------------------
__global__ __launch_bounds__(256) void bscatter_kernel(
    const int* __restrict__ src, const int* __restrict__ dst,
    const int* __restrict__ et, int* __restrict__ bcur,
    unsigned* __restrict__ eidx1, int E, int NB)
{
    __shared__ int cnt[1024];
    __shared__ int bbs[1024];
    int tid = threadIdx.x;
    for (int i = tid; i < NB; i += 256) cnt[i] = 0;
    __syncthreads();
    int base = blockIdx.x * SCAT_Q;
    int lim = E - base; if (lim > SCAT_Q) lim = SCAT_Q;
    for (int i = tid; i < lim; i += 256)
        atomicAdd(&cnt[dst[base + i] >> DLO_BITS], 1);
    __syncthreads();
    for (int i = tid; i < NB; i += 256) {
        int c = cnt[i];
        bbs[i] = c ? atomicAdd(&bcur[i], c) : 0;
    }
    __syncthreads();
    for (int i = tid; i < NB; i += 256) cnt[i] = 0;
    __syncthreads();
    for (int i = tid; i < lim; i += 256) {
        int e = base + i;
        int d = dst[e];
        int bk = d >> DLO_BITS;
        int p = bbs[bk] + atomicAdd(&cnt[bk], 1);
        eidx1[p] = (unsigned)src[e] | ((unsigned)et[e] << 17)
                 | ((unsigned)(d & DLO_MASK) << 19);
    }
}

// ------- per-bucket counting sort by (dlo,et) -> node CSR with et segments ----
__global__ __launch_bounds__(256) void bucket_sort_kernel(
    const unsigned* __restrict__ eidx1, const int* __restrict__ bbase,
    const int* __restrict__ bcnt, unsigned* __restrict__ eidx2,
    int* __restrict__ rp, int* __restrict__ rend0, int* __restrict__ rend1,
    int* __restrict__ rend, int N)
{
    __shared__ int c512[512], excl[512], w[512];
    int tid = threadIdx.x, b = blockIdx.x;
    int gbase = bbase[b], cnt = bcnt[b], n0 = b << DLO_BITS;
    c512[tid] = 0; c512[tid + 256] = 0;
    __syncthreads();
    for (int k = tid; k < cnt; k += 256) {
        unsigned pk = eidx1[gbase + k];
        int key = (((pk >> 19) & DLO_MASK) << 2) | ((pk >> 17) & 3);
        atomicAdd(&c512[key], 1);
    }
    __syncthreads();
    w[tid] = c512[tid]; w[tid + 256] = c512[tid + 256];
    __syncthreads();
    for (int off = 1; off < 512; off <<= 1) {
        int a1 = (tid >= off) ? w[tid - off] : 0;
        int a2 = (tid + 256 >= off) ? w[tid + 256 - off] : 0;
        __syncthreads();
        w[tid] += a1; w[tid + 256] += a2;
        __syncthreads();
    }
    excl[tid] = w[tid] - c512[tid];
    excl[tid + 256] = w[tid + 256] - c512[tid + 256];
    __syncthreads();
    if (tid < 128) {
        int n = n0 + tid;
        if (n < N) {
            int k0 = tid << 2;
            rp[n]    = gbase + excl[k0];
            rend0[n] = gbase + excl[k0 | 1];
            rend1[n] = gbase + excl[k0 | 2];
            rend[n]  = gbase + excl[k0 | 2] + c512[k0 | 2];
        }
    }
    __syncthreads();
    c512[tid] = 0; c512[tid + 256] = 0;
    __syncthreads();
    for (int k = tid; k < cnt; k += 256) {
        unsigned pk = eidx1[gbase + k];
        int key = (((pk >> 19) & DLO_MASK) << 2) | ((pk >> 17) & 3);
        int p = excl[key] + atomicAdd(&c512[key], 1);
        eidx2[gbase + p] = pk;
    }
}

// ---------------- dense layer-1 (round-0 structure: sW + sH staged) -----------
__global__ __launch_bounds__(256) void dense_kernel(
    const float* __restrict__ x,
    const float* __restrict__ W,        // [4][64][32] precomputed
    const float* __restrict__ bias_l,   // [32]
    float* __restrict__ hrel,           // [3][N][32]
    float* __restrict__ agg,            // [N][32]
    int N)
{
    __shared__ float sW[4 * 2048];     // 32 KB
    __shared__ float sH[64 * 68];      // 17 KB
    const int tid = threadIdx.x;
    for (int i = tid; i < 4 * 2048; i += 256) sW[i] = W[i];
    const int nb = blockIdx.x * 64;
    for (int idx = tid; idx < 64 * 64; idx += 256) {
        int n = idx >> 6, i = idx & 63;
        int gn = nb + n;
        sH[n * 68 + i] = (gn < N) ? x[(size_t)gn * 64 + i] : 0.0f;
    }
    __syncthreads();

    const int m  = tid >> 6;       // wave id = which matrix (0..2 rel, 3 loop)
    const int l  = tid & 63;
    const int ow = l & 7;          // output quad: cols ow*4 .. ow*4+3
    const int ng = l >> 3;         // node sub-id: nodes j*8 + ng, j=0..7

    float acc[8][4];
    #pragma unroll
    for (int j = 0; j < 8; ++j)
        #pragma unroll
        for (int k = 0; k < 4; ++k) acc[j][k] = 0.0f;

    const float* wb = &sW[m * 2048 + ow * 4];
    #pragma unroll 2
    for (int i = 0; i < 64; i += 4) {
        float4 wv0 = *(const float4*)(wb + (i + 0) * 32);
        float4 wv1 = *(const float4*)(wb + (i + 1) * 32);
        float4 wv2 = *(const float4*)(wb + (i + 2) * 32);
        float4 wv3 = *(const float4*)(wb + (i + 3) * 32);
        #pragma unroll
        for (int j = 0; j < 8; ++j) {
            float4 hv = *(const float4*)&sH[(j * 8 + ng) * 68 + i];
            acc[j][0] += hv.x * wv0.x + hv.y * wv1.x + hv.z * wv2.x + hv.w * wv3.x;
            acc[j][1] += hv.x * wv0.y + hv.y * wv1.y + hv.z * wv2.y + hv.w * wv3.y;
            acc[j][2] += hv.x * wv0.z + hv.y * wv1.z + hv.z * wv2.z + hv.w * wv3.z;
            acc[j][3] += hv.x * wv0.w + hv.y * wv1.w + hv.z * wv2.w + hv.w * wv3.w;
        }
    }

    if (m < 3) {
        #pragma unroll
        for (int j = 0; j < 8; ++j) {
            int n = nb + j * 8 + ng;
            if (n < N)
                *(float4*)&hrel[((size_t)m * N + n) * 32 + ow * 4] =
                    make_float4(acc[j][0], acc[j][1], acc[j][2], acc[j][3]);
        }
    } else {
        float4 bb = *(const float4*)&bias_l[ow * 4];
        #pragma unroll
        for (int j = 0; j < 8; ++j) {
            int n = nb + j * 8 + ng;
            if (n < N)
                *(float4*)&agg[(size_t)n * 32 + ow * 4] =
                    make_float4(acc[j][0] + bb.x, acc[j][1] + bb.y,
                                acc[j][2] + bb.z, acc[j][3] + bb.w);
        }
    }
}

// ------- layer-1 gather (et-segmented): per segment hrel base is uniform ------
__global__ __launch_bounds__(256) void gather1_kernel(
    const unsigned* __restrict__ eidx, const int* __restrict__ rp,
    const int* __restrict__ rend0, const int* __restrict__ rend1,
    const int* __restrict__ rend,
    const float* __restrict__ hrel, const float* __restrict__ agg,
    float* __restrict__ feat, int N)
{
    int tid = blockIdx.x * 256 + threadIdx.x;
    int n = tid >> 3;
    if (n >= N) return;
    int c = (tid & 7) << 2;
    int e0 = rp[n], e1 = rend0[n], e2 = rend1[n], e3 = rend[n];
    const float4 bv = *(const float4*)&agg[(size_t)n * 32 + c];
    float ax = bv.x, ay = bv.y, az = bv.z, aw = bv.w;
    float bx = 0, by = 0, bz = 0, bw = 0;
    #pragma unroll
    for (int seg = 0; seg < 3; ++seg) {
        int ks = (seg == 0) ? e0 : ((seg == 1) ? e1 : e2);
        int ke = (seg == 0) ? e1 : ((seg == 1) ? e2 : e3);
        const float* hb = hrel + (size_t)seg * N * 32 + c;
        int k = ks;
        for (; k + 2 <= ke; k += 2) {
            unsigned p0 = eidx[k], p1 = eidx[k + 1];
            float4 v0 = *(const float4*)&hb[(size_t)(p0 & 0x1FFFF) * 32];
            float4 v1 = *(const float4*)&hb[(size_t)(p1 & 0x1FFFF) * 32];
            ax += v0.x; ay += v0.y; az += v0.z; aw += v0.w;
            bx += v1.x; by += v1.y; bz += v1.z; bw += v1.w;
        }
        if (k < ke) {
            unsigned p = eidx[k];
            float4 v = *(const float4*)&hb[(size_t)(p & 0x1FFFF) * 32];
            ax += v.x; ay += v.y; az += v.z; aw += v.w;
        }
    }
    float4* out = (float4*)&feat[(size_t)n * 128 + c];
    *out = make_float4(tanhf(ax + bx), tanhf(ay + by), tanhf(az + bz), tanhf(aw + bw));
}

// ------- fused layers 2-4 (et-segmented): sum per segment, 2 FMA per segment --
__global__ __launch_bounds__(256) void fused_layer_kernel(
    const unsigned* __restrict__ eidx, const int* __restrict__ rp,
    const int* __restrict__ rend0, const int* __restrict__ rend1,
    const int* __restrict__ rend,
    const float* __restrict__ basis_b,  // [2][32][32]
    const float* __restrict__ loop_w,   // [32][32]
    const float* __restrict__ bias_l,   // [32]
    const float* __restrict__ comp,     // [3][2]
    const float* __restrict__ feat_in,  // feat + (l-1)*32, stride 128
    float* __restrict__ feat_out,       // feat + l*32,     stride 128
    int N)
{
    __shared__ float sB0[1024], sB1[1024], sL[1024];
    __shared__ float sT0[32 * 36], sT1[32 * 36], sH[32 * 36];
    const int tid = threadIdx.x;
    for (int i = tid; i < 1024; i += 256) {
        sB0[i] = basis_b[i];
        sB1[i] = basis_b[1024 + i];
        sL[i]  = loop_w[i];
    }
    const int nn = tid >> 3, cg = (tid & 7) << 2;
    const int n = blockIdx.x * 32 + nn;

    float4 h4 = *(const float4*)&feat_in[(size_t)n * 128 + cg];
    *(float4*)&sH[nn * 36 + cg] = h4;

    int e0 = rp[n], e1 = rend0[n], e2 = rend1[n], e3 = rend[n];
    float t0x = 0, t0y = 0, t0z = 0, t0w = 0;
    float t1x = 0, t1y = 0, t1z = 0, t1w = 0;
    #pragma unroll
    for (int seg = 0; seg < 3; ++seg) {
        int ks = (seg == 0) ? e0 : ((seg == 1) ? e1 : e2);
        int ke = (seg == 0) ? e1 : ((seg == 1) ? e2 : e3);
        float sx = 0, sy = 0, sz = 0, sw = 0;
        float ux = 0, uy = 0, uz = 0, uw = 0;
        int k = ks;
        for (; k + 2 <= ke; k += 2) {
            unsigned p0 = eidx[k], p1 = eidx[k + 1];
            float4 v0 = *(const float4*)&feat_in[(size_t)(p0 & 0x1FFFF) * 128 + cg];
            float4 v1 = *(const float4*)&feat_in[(size_t)(p1 & 0x1FFFF) * 128 + cg];
            sx += v0.x; sy += v0.y; sz += v0.z; sw += v0.w;
            ux += v1.x; uy += v1.y; uz += v1.z; uw += v1.w;
        }
        if (k < ke) {
            unsigned p = eidx[k];
            float4 v = *(const float4*)&feat_in[(size_t)(p & 0x1FFFF) * 128 + cg];
            sx += v.x; sy += v.y; sz += v.z; sw += v.w;
        }
        sx += ux; sy += uy; sz += uz; sw += uw;
        float c0 = comp[seg * 2], c1 = comp[seg * 2 + 1];
        t0x += c0 * sx; t0y += c0 * sy; t0z += c0 * sz; t0w += c0 * sw;
        t1x += c1 * sx; t1y += c1 * sy; t1z += c1 * sz; t1w += c1 * sw;
    }
    *(float4*)&sT0[nn * 36 + cg] = make_float4(t0x, t0y, t0z, t0w);
    *(float4*)&sT1[nn * 36 + cg] = make_float4(t1x, t1y, t1z, t1w);
    __syncthreads();

    float4 bb = *(const float4*)&bias_l[cg];
    float a[4] = {bb.x, bb.y, bb.z, bb.w};
    #pragma unroll 8
    for (int kk = 0; kk < 32; ++kk) {
        float p0 = sT0[nn * 36 + kk];
        float p1 = sT1[nn * 36 + kk];
        float hh = sH[nn * 36 + kk];
        float4 b0 = *(const float4*)&sB0[kk * 32 + cg];
        float4 b1 = *(const float4*)&sB1[kk * 32 + cg];
        float4 lw = *(const float4*)&sL[kk * 32 + cg];
        a[0] += p0 * b0.x + p1 * b1.x + hh * lw.x;
        a[1] += p0 * b0.y + p1 * b1.y + hh * lw.y;
        a[2] += p0 * b0.z + p1 * b1.z + hh * lw.z;
        a[3] += p0 * b0.w + p1 * b1.w + hh * lw.w;
    }
    *(float4*)&feat_out[(size_t)n * 128 + cg] =
        make_float4(tanhf(a[0]), tanhf(a[1]), tanhf(a[2]), tanhf(a[3]));
}

// ------- pooling: node-chunk blocks, run-accumulate, atomic flush ----------
__global__ __launch_bounds__(256) void pool_kernel(
    const float* __restrict__ feat, const int* __restrict__ gid,
    float* __restrict__ pooled, float* __restrict__ cntArr, int N)
{
    int chunk0 = blockIdx.x * 128;
    int ch = threadIdx.x & 127, half = threadIdx.x >> 7;
    int n = chunk0 + half;
    int lim = chunk0 + 128; if (lim > N) lim = N;
    if (n >= lim) return;
    int cur = gid[n];
    float acc = 0.0f; int cc = 0;
    for (; n < lim; n += 2) {
        int g = gid[n];
        if (g != cur) {
            atomicAdd(&pooled[(size_t)cur * 128 + ch], acc);
            if (ch == 0) atomicAdd(&cntArr[cur], (float)cc);
            acc = 0.0f; cc = 0; cur = g;
        }
        acc += feat[(size_t)n * 128 + ch];
        ++cc;
    }
    atomicAdd(&pooled[(size_t)cur * 128 + ch], acc);
    if (ch == 0) atomicAdd(&cntArr[cur], (float)cc);
}

// ---------------- final MLP (divides pooled sums by counts) -------------------
__global__ __launch_bounds__(64) void mlp_kernel(
    const float* __restrict__ pooled, const float* __restrict__ cntArr,
    const float* __restrict__ w1, const float* __restrict__ b1,
    const float* __restrict__ w2, const float* __restrict__ b2,
    float* __restrict__ out)
{
    int g = blockIdx.x;
    int t = threadIdx.x;  // 64
    float inv = 1.0f / fmaxf(cntArr[g], 1.0f);
    float acc = b1[t];
    #pragma unroll 8
    for (int k = 0; k < 128; ++k)
        acc += pooled[(size_t)g * 128 + k] * inv * w1[k * 64 + t];
    float h = fmaxf(acc, 0.0f);
    float p = h * w2[t];
    #pragma unroll
    for (int off = 32; off > 0; off >>= 1) p += __shfl_down(p, off, 64);
    if (t == 0) out[g] = 1.0f / (1.0f + expf(-(p + b2[0])));
}

extern "C" void kernel_launch(void* const* d_in, const int* in_sizes, int n_in,
                              void* d_out, int out_size, void* d_ws, size_t ws_size,
                              hipStream_t stream)
{
    const float* x       = (const float*)d_in[0];
    const float* basis1  = (const float*)d_in[1];
    const float* basis_r = (const float*)d_in[2];
    const float* w_comp  = (const float*)d_in[3];
    const float* loop1   = (const float*)d_in[4];
    const float* loop_r  = (const float*)d_in[5];
    const float* bias    = (const float*)d_in[6];
    const float* lin1_w  = (const float*)d_in[7];
    const float* lin1_b  = (const float*)d_in[8];
    const float* lin2_w  = (const float*)d_in[9];
    const float* lin2_b  = (const float*)d_in[10];
    const int*   src     = (const int*)d_in[11];
    const int*   dst     = (const int*)d_in[12];
    const int*   etype   = (const int*)d_in[13];
    const int*   gid     = (const int*)d_in[14];

    const int N = in_sizes[0] / 64;
    const int E = in_sizes[11];
    const int G = out_size;  // 256
    const int NB = (N + DLO_MASK) >> DLO_BITS;  // 782

    // workspace layout (words):
    // W[8192] | hrel[3*N*32] | agg[N*32] | feat[N*128] | pooled[G*128] | cntArr[G]
    // | bcnt[NB] | bbase[NB] | bcur[NB] | rp[N] | rend0[N] | rend1[N] | rend[N] | eidx2[E]
    // eidx1 aliases feat (consumed by bucket_sort before gather1 writes feat)
    float* ws      = (float*)d_ws;
    float* W       = ws;                          // 8192
    float* hrel    = W + 8192;                    // 3*N*32
    float* agg     = hrel + (size_t)3 * N * 32;   // N*32
    float* feat    = agg + (size_t)N * 32;        // N*128
    float* pooled  = feat + (size_t)N * 128;      // G*128
    float* cntArr  = pooled + (size_t)G * 128;    // G
    int*   bcnt    = (int*)(cntArr + G);          // NB
    int*   bbase   = bcnt + NB;                   // NB
    int*   bcur    = bbase + NB;                  // NB
    int*   rp      = bcur + NB;                   // N
    int*   rend0   = rp + N;                      // N
    int*   rend1   = rend0 + N;                   // N
    int*   rend    = rend1 + N;                   // N
    unsigned* eidx2 = (unsigned*)(rend + N);      // E
    unsigned* eidx1 = (unsigned*)feat;            // alias

    // zero pooled + cntArr + bcnt in one shot (contiguous)
    hipMemsetAsync(pooled, 0, ((size_t)G * 128 + G + NB) * sizeof(float), stream);
    prep_w<<<32, 256, 0, stream>>>(basis1, w_comp, loop1, W);

    // CSR build: count -> scan -> bucketed scatter -> (dlo,et) counting sort
    const int nsb = (E + SCAT_Q - 1) / SCAT_Q;    // 782 blocks
    count_kernel<<<nsb, 256, 0, stream>>>(dst, bcnt, E, NB);
    scan_kernel<<<1, 1024, 0, stream>>>(bcnt, bbase, bcur, NB);
    bscatter_kernel<<<nsb, 256, 0, stream>>>(src, dst, etype, bcur, eidx1, E, NB);
    bucket_sort_kernel<<<NB, 256, 0, stream>>>(eidx1, bbase, bcnt, eidx2,
                                               rp, rend0, rend1, rend, N);

    // layer 1: dense (staged weights + x) + segmented register gather
    dense_kernel<<<(N + 63) / 64, 256, 0, stream>>>(x, W, bias, hrel, agg, N);
    gather1_kernel<<<(N * 8 + 255) / 256, 256, 0, stream>>>(
        eidx2, rp, rend0, rend1, rend, hrel, agg, feat, N);

    // layers 2-4: segmented gather (sum per segment) + in-LDS matmuls + tanh
    for (int l = 1; l < 4; ++l) {
        fused_layer_kernel<<<(N + 31) / 32, 256, 0, stream>>>(
            eidx2, rp, rend0, rend1, rend,
            basis_r + (size_t)(l - 1) * 2048,
            loop_r + (size_t)(l - 1) * 1024,
            bias + l * 32,
            w_comp + l * 6,
            feat + (l - 1) * 32,
            feat + l * 32,
            N);
    }

    pool_kernel<<<(N + 127) / 128, 256, 0, stream>>>(feat, gid, pooled, cntArr, N);
    mlp_kernel<<<G, 64, 0, stream>>>(pooled, cntArr, lin1_w, lin1_b, lin2_w, lin2_b, (float*)d_out);
}

// Round 6
// 324.558 us; speedup vs baseline: 1.1091x; 1.1091x over previous
//
#include <hip/hip_runtime.h>
#include <cstdint>
#include <cmath>

// Problem constants: N=100000, IN=64, HID=32, R=3, B=2, E=1600000, G=256, 4 layers
// CSR build v4: single-owner-write partition.
//   part_kernel: per 4096-edge chunk, LDS counting sort by bucket -> chunk-local
//     contiguous output (no cross-XCD partial-line write amplification) + run
//     start table + global bucket totals.
//   scan_kernel: bucket bases.
//   bucket_sort_kernel: per bucket, gather runs (bsearch over cum lengths),
//     counting sort by (dlo,et) -> eidx2 (single-owner region) + segmented CSR.
#define DLO_BITS 7
#define DLO_MASK 127
#define CHUNK 4096

// ---------------- weight prep: W[m] = sum_b comp[m,b]*basis1[b]; W[3]=loop1 ---
__global__ __launch_bounds__(256) void prep_w(
    const float* __restrict__ basis1,   // [2,64,32]
    const float* __restrict__ w_comp,   // [4,3,2] (layer-0 slice)
    const float* __restrict__ loop1,    // [64,32]
    float* __restrict__ W)              // [4,64,32]
{
    int tid = blockIdx.x * 256 + threadIdx.x;
    if (tid < 8192) {
        int m = tid >> 11, io = tid & 2047;
        W[tid] = (m < 3)
            ? w_comp[m * 2] * basis1[io] + w_comp[m * 2 + 1] * basis1[2048 + io]
            : loop1[io];
    }
}

// ---------------- partition: chunk-local counting sort by bucket --------------
__global__ __launch_bounds__(256) void part_kernel(
    const int* __restrict__ src, const int* __restrict__ dst,
    const int* __restrict__ et, unsigned* __restrict__ eidx1,
    int* __restrict__ startTab,   // [NCH][NB+1] run starts (+sentinel)
    int* __restrict__ bcnt,       // [NB] global bucket totals (pre-zeroed)
    int E, int NB)
{
    __shared__ unsigned rec[CHUNK];   // 16 KB
    __shared__ int cnt[1024];         // 4 KB
    __shared__ int w[1024];           // 4 KB
    const int tid = threadIdx.x;
    const int base = blockIdx.x * CHUNK;
    int lim = E - base; if (lim > CHUNK) lim = CHUNK;

    cnt[tid] = 0; cnt[tid + 256] = 0; cnt[tid + 512] = 0; cnt[tid + 768] = 0;
    __syncthreads();
    for (int i = tid; i < lim; i += 256) {
        int e = base + i;
        int d = dst[e];
        rec[i] = (unsigned)src[e] | ((unsigned)et[e] << 17)
               | ((unsigned)(d & DLO_MASK) << 19);
        atomicAdd(&cnt[d >> DLO_BITS], 1);
    }
    __syncthreads();
    w[tid] = cnt[tid]; w[tid + 256] = cnt[tid + 256];
    w[tid + 512] = cnt[tid + 512]; w[tid + 768] = cnt[tid + 768];
    __syncthreads();
    for (int off = 1; off < 1024; off <<= 1) {
        int a0 = (tid >= off) ? w[tid - off] : 0;
        int a1 = (tid + 256 >= off) ? w[tid + 256 - off] : 0;
        int a2 = (tid + 512 >= off) ? w[tid + 512 - off] : 0;
        int a3 = w[tid + 768 - off];
        __syncthreads();
        w[tid] += a0; w[tid + 256] += a1; w[tid + 512] += a2; w[tid + 768] += a3;
        __syncthreads();
    }
    // excl offsets into w, start table, global totals
    int* st = startTab + blockIdx.x * (NB + 1);
    for (int bk = tid; bk < NB; bk += 256) {
        int c = cnt[bk];
        int ex = w[bk] - c;
        st[bk] = base + ex;
        w[bk] = ex;
        if (c) atomicAdd(&bcnt[bk], c);
    }
    if (tid == 0) st[NB] = base + lim;
    __syncthreads();
    cnt[tid] = 0; cnt[tid + 256] = 0; cnt[tid + 512] = 0; cnt[tid + 768] = 0;
    __syncthreads();
    // scatter into OWN contiguous region (single-owner lines -> no amplification)
    for (int i = tid; i < lim; i += 256) {
        int bk = dst[base + i] >> DLO_BITS;
        int pos = w[bk] + atomicAdd(&cnt[bk], 1);
        eidx1[base + pos] = rec[i];
    }
}

// ---------------- exclusive scan over NB (<=1024) buckets ---------------------
__global__ __launch_bounds__(1024) void scan_kernel(
    const int* __restrict__ bcnt, int* __restrict__ bbase, int NB)
{
    __shared__ int s[1024];
    int t = threadIdx.x;
    int v = (t < NB) ? bcnt[t] : 0;
    s[t] = v; __syncthreads();
    for (int off = 1; off < 1024; off <<= 1) {
        int u = (t >= off) ? s[t - off] : 0;
        __syncthreads();
        s[t] += u;
        __syncthreads();
    }
    if (t < NB) bbase[t] = s[t] - v;
}

// ------- per-bucket: gather runs + counting sort by (dlo,et) -> segmented CSR -
__global__ __launch_bounds__(256) void bucket_sort_kernel(
    const unsigned* __restrict__ eidx1, const int* __restrict__ startTab,
    const int* __restrict__ bbase, unsigned* __restrict__ eidx2,
    int* __restrict__ rp, int* __restrict__ rend0, int* __restrict__ rend1,
    int* __restrict__ rend, int N, int NCH, int NB)
{
    __shared__ int rbase[512];    // run global start addresses
    __shared__ int racc[512];     // inclusive cumulative run lengths
    __shared__ int c512[512], excl[512], w2[512];
    const int tid = threadIdx.x, b = blockIdx.x;

    for (int j = tid; j < 512; j += 256) {
        int s = 0, len = 0;
        if (j < NCH) {
            s = startTab[j * (NB + 1) + b];
            len = startTab[j * (NB + 1) + b + 1] - s;
        }
        rbase[j] = s;
        racc[j] = len;
    }
    __syncthreads();
    for (int off = 1; off < 512; off <<= 1) {
        int a1 = (tid >= off) ? racc[tid - off] : 0;
        int a2 = (tid + 256 >= off) ? racc[tid + 256 - off] : 0;
        __syncthreads();
        racc[tid] += a1; racc[tid + 256] += a2;
        __syncthreads();
    }
    const int cnt = racc[NCH - 1];
    const int gbase = bbase[b];
    c512[tid] = 0; c512[tid + 256] = 0;
    __syncthreads();
    for (int i = tid; i < cnt; i += 256) {
        int lo = 0, hi = NCH - 1;
        while (lo < hi) { int mid = (lo + hi) >> 1; if (racc[mid] <= i) lo = mid + 1; else hi = mid; }
        unsigned pk = eidx1[rbase[lo] + (i - (lo ? racc[lo - 1] : 0))];
        int key = (((pk >> 19) & DLO_MASK) << 2) | ((pk >> 17) & 3);
        atomicAdd(&c512[key], 1);
    }
    __syncthreads();
    w2[tid] = c512[tid]; w2[tid + 256] = c512[tid + 256];
    __syncthreads();
    for (int off = 1; off < 512; off <<= 1) {
        int a1 = (tid >= off) ? w2[tid - off] : 0;
        int a2 = (tid + 256 >= off) ? w2[tid + 256 - off] : 0;
        __syncthreads();
        w2[tid] += a1; w2[tid + 256] += a2;
        __syncthreads();
    }
    excl[tid] = w2[tid] - c512[tid];
    excl[tid + 256] = w2[tid + 256] - c512[tid + 256];
    __syncthreads();
    if (tid < 128) {
        int n = (b << DLO_BITS) + tid;
        if (n < N) {
            int k0 = tid << 2;
            rp[n]    = gbase + excl[k0];
            rend0[n] = gbase + excl[k0 | 1];
            rend1[n] = gbase + excl[k0 | 2];
            rend[n]  = gbase + excl[k0 | 2] + c512[k0 | 2];
        }
    }
    __syncthreads();
    c512[tid] = 0; c512[tid + 256] = 0;
    __syncthreads();
    for (int i = tid; i < cnt; i += 256) {
        int lo = 0, hi = NCH - 1;
        while (lo < hi) { int mid = (lo + hi) >> 1; if (racc[mid] <= i) lo = mid + 1; else hi = mid; }
        unsigned pk = eidx1[rbase[lo] + (i - (lo ? racc[lo - 1] : 0))];
        int key = (((pk >> 19) & DLO_MASK) << 2) | ((pk >> 17) & 3);
        int p = excl[key] + atomicAdd(&c512[key], 1);
        eidx2[gbase + p] = pk;
    }
}

// ---------------- dense layer-1 (round-0 structure: sW + sH staged) -----------
__global__ __launch_bounds__(256) void dense_kernel(
    const float* __restrict__ x,
    const float* __restrict__ W,        // [4][64][32] precomputed
    const float* __restrict__ bias_l,   // [32]
    float* __restrict__ hrel,           // [3][N][32]
    float* __restrict__ agg,            // [N][32]
    int N)
{
    __shared__ float sW[4 * 2048];     // 32 KB
    __shared__ float sH[64 * 68];      // 17 KB
    const int tid = threadIdx.x;
    for (int i = tid; i < 4 * 2048; i += 256) sW[i] = W[i];
    const int nb = blockIdx.x * 64;
    for (int idx = tid; idx < 64 * 64; idx += 256) {
        int n = idx >> 6, i = idx & 63;
        int gn = nb + n;
        sH[n * 68 + i] = (gn < N) ? x[(size_t)gn * 64 + i] : 0.0f;
    }
    __syncthreads();

    const int m  = tid >> 6;
    const int l  = tid & 63;
    const int ow = l & 7;
    const int ng = l >> 3;

    float acc[8][4];
    #pragma unroll
    for (int j = 0; j < 8; ++j)
        #pragma unroll
        for (int k = 0; k < 4; ++k) acc[j][k] = 0.0f;

    const float* wb = &sW[m * 2048 + ow * 4];
    #pragma unroll 2
    for (int i = 0; i < 64; i += 4) {
        float4 wv0 = *(const float4*)(wb + (i + 0) * 32);
        float4 wv1 = *(const float4*)(wb + (i + 1) * 32);
        float4 wv2 = *(const float4*)(wb + (i + 2) * 32);
        float4 wv3 = *(const float4*)(wb + (i + 3) * 32);
        #pragma unroll
        for (int j = 0; j < 8; ++j) {
            float4 hv = *(const float4*)&sH[(j * 8 + ng) * 68 + i];
            acc[j][0] += hv.x * wv0.x + hv.y * wv1.x + hv.z * wv2.x + hv.w * wv3.x;
            acc[j][1] += hv.x * wv0.y + hv.y * wv1.y + hv.z * wv2.y + hv.w * wv3.y;
            acc[j][2] += hv.x * wv0.z + hv.y * wv1.z + hv.z * wv2.z + hv.w * wv3.z;
            acc[j][3] += hv.x * wv0.w + hv.y * wv1.w + hv.z * wv2.w + hv.w * wv3.w;
        }
    }

    if (m < 3) {
        #pragma unroll
        for (int j = 0; j < 8; ++j) {
            int n = nb + j * 8 + ng;
            if (n < N)
                *(float4*)&hrel[((size_t)m * N + n) * 32 + ow * 4] =
                    make_float4(acc[j][0], acc[j][1], acc[j][2], acc[j][3]);
        }
    } else {
        float4 bb = *(const float4*)&bias_l[ow * 4];
        #pragma unroll
        for (int j = 0; j < 8; ++j) {
            int n = nb + j * 8 + ng;
            if (n < N)
                *(float4*)&agg[(size_t)n * 32 + ow * 4] =
                    make_float4(acc[j][0] + bb.x, acc[j][1] + bb.y,
                                acc[j][2] + bb.z, acc[j][3] + bb.w);
        }
    }
}

// ------- layer-1 gather (et-segmented): per segment hrel base is uniform ------
__global__ __launch_bounds__(256) void gather1_kernel(
    const unsigned* __restrict__ eidx, const int* __restrict__ rp,
    const int* __restrict__ rend0, const int* __restrict__ rend1,
    const int* __restrict__ rend,
    const float* __restrict__ hrel, const float* __restrict__ agg,
    float* __restrict__ feat, int N)
{
    int tid = blockIdx.x * 256 + threadIdx.x;
    int n = tid >> 3;
    if (n >= N) return;
    int c = (tid & 7) << 2;
    int e0 = rp[n], e1 = rend0[n], e2 = rend1[n], e3 = rend[n];
    const float4 bv = *(const float4*)&agg[(size_t)n * 32 + c];
    float ax = bv.x, ay = bv.y, az = bv.z, aw = bv.w;
    float bx = 0, by = 0, bz = 0, bw = 0;
    #pragma unroll
    for (int seg = 0; seg < 3; ++seg) {
        int ks = (seg == 0) ? e0 : ((seg == 1) ? e1 : e2);
        int ke = (seg == 0) ? e1 : ((seg == 1) ? e2 : e3);
        const float* hb = hrel + (size_t)seg * N * 32 + c;
        int k = ks;
        for (; k + 2 <= ke; k += 2) {
            unsigned p0 = eidx[k], p1 = eidx[k + 1];
            float4 v0 = *(const float4*)&hb[(size_t)(p0 & 0x1FFFF) * 32];
            float4 v1 = *(const float4*)&hb[(size_t)(p1 & 0x1FFFF) * 32];
            ax += v0.x; ay += v0.y; az += v0.z; aw += v0.w;
            bx += v1.x; by += v1.y; bz += v1.z; bw += v1.w;
        }
        if (k < ke) {
            unsigned p = eidx[k];
            float4 v = *(const float4*)&hb[(size_t)(p & 0x1FFFF) * 32];
            ax += v.x; ay += v.y; az += v.z; aw += v.w;
        }
    }
    float4* out = (float4*)&feat[(size_t)n * 128 + c];
    *out = make_float4(tanhf(ax + bx), tanhf(ay + by), tanhf(az + bz), tanhf(aw + bw));
}

// ------- fused layers 2-4 (et-segmented): sum per segment, 2 FMA per segment --
__global__ __launch_bounds__(256) void fused_layer_kernel(
    const unsigned* __restrict__ eidx, const int* __restrict__ rp,
    const int* __restrict__ rend0, const int* __restrict__ rend1,
    const int* __restrict__ rend,
    const float* __restrict__ basis_b,  // [2][32][32]
    const float* __restrict__ loop_w,   // [32][32]
    const float* __restrict__ bias_l,   // [32]
    const float* __restrict__ comp,     // [3][2]
    const float* __restrict__ feat_in,  // feat + (l-1)*32, stride 128
    float* __restrict__ feat_out,       // feat + l*32,     stride 128
    int N)
{
    __shared__ float sB0[1024], sB1[1024], sL[1024];
    __shared__ float sT0[32 * 36], sT1[32 * 36], sH[32 * 36];
    const int tid = threadIdx.x;
    for (int i = tid; i < 1024; i += 256) {
        sB0[i] = basis_b[i];
        sB1[i] = basis_b[1024 + i];
        sL[i]  = loop_w[i];
    }
    const int nn = tid >> 3, cg = (tid & 7) << 2;
    const int n = blockIdx.x * 32 + nn;

    float4 h4 = *(const float4*)&feat_in[(size_t)n * 128 + cg];
    *(float4*)&sH[nn * 36 + cg] = h4;

    int e0 = rp[n], e1 = rend0[n], e2 = rend1[n], e3 = rend[n];
    float t0x = 0, t0y = 0, t0z = 0, t0w = 0;
    float t1x = 0, t1y = 0, t1z = 0, t1w = 0;
    #pragma unroll
    for (int seg = 0; seg < 3; ++seg) {
        int ks = (seg == 0) ? e0 : ((seg == 1) ? e1 : e2);
        int ke = (seg == 0) ? e1 : ((seg == 1) ? e2 : e3);
        float sx = 0, sy = 0, sz = 0, sw = 0;
        float ux = 0, uy = 0, uz = 0, uw = 0;
        int k = ks;
        for (; k + 2 <= ke; k += 2) {
            unsigned p0 = eidx[k], p1 = eidx[k + 1];
            float4 v0 = *(const float4*)&feat_in[(size_t)(p0 & 0x1FFFF) * 128 + cg];
            float4 v1 = *(const float4*)&feat_in[(size_t)(p1 & 0x1FFFF) * 128 + cg];
            sx += v0.x; sy += v0.y; sz += v0.z; sw += v0.w;
            ux += v1.x; uy += v1.y; uz += v1.z; uw += v1.w;
        }
        if (k < ke) {
            unsigned p = eidx[k];
            float4 v = *(const float4*)&feat_in[(size_t)(p & 0x1FFFF) * 128 + cg];
            sx += v.x; sy += v.y; sz += v.z; sw += v.w;
        }
        sx += ux; sy += uy; sz += uz; sw += uw;
        float c0 = comp[seg * 2], c1 = comp[seg * 2 + 1];
        t0x += c0 * sx; t0y += c0 * sy; t0z += c0 * sz; t0w += c0 * sw;
        t1x += c1 * sx; t1y += c1 * sy; t1z += c1 * sz; t1w += c1 * sw;
    }
    *(float4*)&sT0[nn * 36 + cg] = make_float4(t0x, t0y, t0z, t0w);
    *(float4*)&sT1[nn * 36 + cg] = make_float4(t1x, t1y, t1z, t1w);
    __syncthreads();

    float4 bb = *(const float4*)&bias_l[cg];
    float a[4] = {bb.x, bb.y, bb.z, bb.w};
    #pragma unroll 8
    for (int kk = 0; kk < 32; ++kk) {
        float p0 = sT0[nn * 36 + kk];
        float p1 = sT1[nn * 36 + kk];
        float hh = sH[nn * 36 + kk];
        float4 b0 = *(const float4*)&sB0[kk * 32 + cg];
        float4 b1 = *(const float4*)&sB1[kk * 32 + cg];
        float4 lw = *(const float4*)&sL[kk * 32 + cg];
        a[0] += p0 * b0.x + p1 * b1.x + hh * lw.x;
        a[1] += p0 * b0.y + p1 * b1.y + hh * lw.y;
        a[2] += p0 * b0.z + p1 * b1.z + hh * lw.z;
        a[3] += p0 * b0.w + p1 * b1.w + hh * lw.w;
    }
    *(float4*)&feat_out[(size_t)n * 128 + cg] =
        make_float4(tanhf(a[0]), tanhf(a[1]), tanhf(a[2]), tanhf(a[3]));
}

// ------- pooling: node-chunk blocks, run-accumulate, atomic flush ----------
__global__ __launch_bounds__(256) void pool_kernel(
    const float* __restrict__ feat, const int* __restrict__ gid,
    float* __restrict__ pooled, float* __restrict__ cntArr, int N)
{
    int chunk0 = blockIdx.x * 128;
    int ch = threadIdx.x & 127, half = threadIdx.x >> 7;
    int n = chunk0 + half;
    int lim = chunk0 + 128; if (lim > N) lim = N;
    if (n >= lim) return;
    int cur = gid[n];
    float acc = 0.0f; int cc = 0;
    for (; n < lim; n += 2) {
        int g = gid[n];
        if (g != cur) {
            atomicAdd(&pooled[(size_t)cur * 128 + ch], acc);
            if (ch == 0) atomicAdd(&cntArr[cur], (float)cc);
            acc = 0.0f; cc = 0; cur = g;
        }
        acc += feat[(size_t)n * 128 + ch];
        ++cc;
    }
    atomicAdd(&pooled[(size_t)cur * 128 + ch], acc);
    if (ch == 0) atomicAdd(&cntArr[cur], (float)cc);
}

// ---------------- final MLP (divides pooled sums by counts) -------------------
__global__ __launch_bounds__(64) void mlp_kernel(
    const float* __restrict__ pooled, const float* __restrict__ cntArr,
    const float* __restrict__ w1, const float* __restrict__ b1,
    const float* __restrict__ w2, const float* __restrict__ b2,
    float* __restrict__ out)
{
    int g = blockIdx.x;
    int t = threadIdx.x;  // 64
    float inv = 1.0f / fmaxf(cntArr[g], 1.0f);
    float acc = b1[t];
    #pragma unroll 8
    for (int k = 0; k < 128; ++k)
        acc += pooled[(size_t)g * 128 + k] * inv * w1[k * 64 + t];
    float h = fmaxf(acc, 0.0f);
    float p = h * w2[t];
    #pragma unroll
    for (int off = 32; off > 0; off >>= 1) p += __shfl_down(p, off, 64);
    if (t == 0) out[g] = 1.0f / (1.0f + expf(-(p + b2[0])));
}

extern "C" void kernel_launch(void* const* d_in, const int* in_sizes, int n_in,
                              void* d_out, int out_size, void* d_ws, size_t ws_size,
                              hipStream_t stream)
{
    const float* x       = (const float*)d_in[0];
    const float* basis1  = (const float*)d_in[1];
    const float* basis_r = (const float*)d_in[2];
    const float* w_comp  = (const float*)d_in[3];
    const float* loop1   = (const float*)d_in[4];
    const float* loop_r  = (const float*)d_in[5];
    const float* bias    = (const float*)d_in[6];
    const float* lin1_w  = (const float*)d_in[7];
    const float* lin1_b  = (const float*)d_in[8];
    const float* lin2_w  = (const float*)d_in[9];
    const float* lin2_b  = (const float*)d_in[10];
    const int*   src     = (const int*)d_in[11];
    const int*   dst     = (const int*)d_in[12];
    const int*   etype   = (const int*)d_in[13];
    const int*   gid     = (const int*)d_in[14];

    const int N = in_sizes[0] / 64;
    const int E = in_sizes[11];
    const int G = out_size;  // 256
    const int NB = (N + DLO_MASK) >> DLO_BITS;    // 782
    const int NCH = (E + CHUNK - 1) / CHUNK;      // 391

    // workspace layout (words):
    // W[8192] | hrel[3*N*32] | agg[N*32] | feat[N*128] | pooled[G*128] | cntArr[G]
    // | bcnt[NB] | bbase[NB] | rp[N] | rend0[N] | rend1[N] | rend[N] | eidx2[E]
    // eidx1 + startTab alias feat (consumed by bucket_sort before gather1 writes)
    float* ws      = (float*)d_ws;
    float* W       = ws;                          // 8192
    float* hrel    = W + 8192;                    // 3*N*32
    float* agg     = hrel + (size_t)3 * N * 32;   // N*32
    float* feat    = agg + (size_t)N * 32;        // N*128
    float* pooled  = feat + (size_t)N * 128;      // G*128
    float* cntArr  = pooled + (size_t)G * 128;    // G
    int*   bcnt    = (int*)(cntArr + G);          // NB
    int*   bbase   = bcnt + NB;                   // NB
    int*   rp      = bbase + NB;                  // N
    int*   rend0   = rp + N;                      // N
    int*   rend1   = rend0 + N;                   // N
    int*   rend    = rend1 + N;                   // N
    unsigned* eidx2 = (unsigned*)(rend + N);      // E
    unsigned* eidx1 = (unsigned*)feat;            // NCH*CHUNK (alias)
    int* startTab  = (int*)feat + (size_t)NCH * CHUNK;  // NCH*(NB+1) (alias)

    // zero pooled + cntArr + bcnt in one shot (contiguous)
    hipMemsetAsync(pooled, 0, ((size_t)G * 128 + G + NB) * sizeof(float), stream);
    prep_w<<<32, 256, 0, stream>>>(basis1, w_comp, loop1, W);

    // CSR build: partition (local sort, single-owner writes) -> scan -> bucket sort
    part_kernel<<<NCH, 256, 0, stream>>>(src, dst, etype, eidx1, startTab, bcnt, E, NB);
    scan_kernel<<<1, 1024, 0, stream>>>(bcnt, bbase, NB);
    bucket_sort_kernel<<<NB, 256, 0, stream>>>(eidx1, startTab, bbase, eidx2,
                                               rp, rend0, rend1, rend, N, NCH, NB);

    // layer 1: dense (staged weights + x) + segmented register gather
    dense_kernel<<<(N + 63) / 64, 256, 0, stream>>>(x, W, bias, hrel, agg, N);
    gather1_kernel<<<(N * 8 + 255) / 256, 256, 0, stream>>>(
        eidx2, rp, rend0, rend1, rend, hrel, agg, feat, N);

    // layers 2-4: segmented gather (sum per segment) + in-LDS matmuls + tanh
    for (int l = 1; l < 4; ++l) {
        fused_layer_kernel<<<(N + 31) / 32, 256, 0, stream>>>(
            eidx2, rp, rend0, rend1, rend,
            basis_r + (size_t)(l - 1) * 2048,
            loop_r + (size_t)(l - 1) * 1024,
            bias + l * 32,
            w_comp + l * 6,
            feat + (l - 1) * 32,
            feat + l * 32,
            N);
    }

    pool_kernel<<<(N + 127) / 128, 256, 0, stream>>>(feat, gid, pooled, cntArr, N);
    mlp_kernel<<<G, 64, 0, stream>>>(pooled, cntArr, lin1_w, lin1_b, lin2_w, lin2_b, (float*)d_out);
}